// Round 13
// baseline (273.179 us; speedup 1.0000x reference)
//
#include <hip/hip_runtime.h>
#include <hip/hip_bf16.h>

#define HIDC 768
#define Hh   6
#define Dd   64
#define AHc  384
#define KSc  9
#define PADc 4
#define Bb   4
#define Ss   1024
#define MRr  (Bb * Ss)          // 4096

typedef __attribute__((ext_vector_type(8))) __bf16 bf16x8;
typedef __attribute__((ext_vector_type(4))) __bf16 bf16x4;
typedef __attribute__((ext_vector_type(4))) float  f32x4;

// async global->LDS, 16 bytes per lane; dest = wave-uniform base + lane*16
__device__ __forceinline__ void gl_lds16(const void* g, void* l) {
    __builtin_amdgcn_global_load_lds(
        (const __attribute__((address_space(1))) void*)g,
        (__attribute__((address_space(3))) void*)l, 16, 0, 0);
}

// split 8 consecutive f32 into hi/lo bf16 fragments
__device__ __forceinline__ void split8r(const float* xs, bf16x8& hi, bf16x8& lo) {
#pragma unroll
    for (int e = 0; e < 8; ++e) {
        __bf16 hv = (__bf16)xs[e];
        hi[e] = hv;
        lo[e] = (__bf16)(xs[e] - (float)hv);
    }
}

// convert 8 consecutive f32 to bf16 (hi only)
__device__ __forceinline__ bf16x8 cvt8(const float* p) {
    float4 x0 = *(const float4*)p;
    float4 x1 = *(const float4*)(p + 4);
    float xs[8] = {x0.x, x0.y, x0.z, x0.w, x1.x, x1.y, x1.z, x1.w};
    bf16x8 h;
#pragma unroll
    for (int e = 0; e < 8; ++e) h[e] = (__bf16)xs[e];
    return h;
}

// ============ fused preprocessing: wsplit_t + pw cvt + bias + td + depthwise ====
// blocks [0,288): wsplit_t; [288,432): pw cvt; [432,440): bias; [440,444): td;
// [444, 444+3072): depthwise. (Q/V pre-convert deleted: gemm stages f32 directly.)
__global__ __launch_bounds__(256) void k_pre(
        const float* __restrict__ Wq, const float* __restrict__ Wk,
        const float* __restrict__ Wv, const float* __restrict__ coW,
        const float* __restrict__ pww, const float* __restrict__ cob,
        const float* __restrict__ sepb, const float* __restrict__ td,
        const int* __restrict__ mask, const float* __restrict__ Kin,
        const float* __restrict__ dww,
        __bf16* __restrict__ Whi,
        float* __restrict__ biasb, float* __restrict__ td_sm,
        __bf16* __restrict__ dwbf) {
    __shared__ float shmem[64 * 65];
    int bid = blockIdx.x;
    int tid = threadIdx.x;
    if (bid < 288) {
        // ---- transposed weight convert ----
        int z = bid / 72, rem = bid % 72;
        int n0 = (rem % 6) * 64, k0 = (rem / 6) * 64;
        const float* src = (z == 0) ? Wq : (z == 1) ? Wk : (z == 2) ? Wv : coW;
        float (*tile)[65] = (float(*)[65])shmem;
        int r = tid >> 2, cq = tid & 3;
#pragma unroll
        for (int e = 0; e < 4; ++e) {
            float4 v = *(const float4*)&src[(size_t)(k0 + r) * AHc + n0 + cq * 16 + e * 4];
            tile[r][cq * 16 + e * 4 + 0] = v.x;
            tile[r][cq * 16 + e * 4 + 1] = v.y;
            tile[r][cq * 16 + e * 4 + 2] = v.z;
            tile[r][cq * 16 + e * 4 + 3] = v.w;
        }
        __syncthreads();
        float x[16];
#pragma unroll
        for (int e = 0; e < 16; ++e) x[e] = tile[cq * 16 + e][r];
        bf16x8 h0, h1;
#pragma unroll
        for (int e = 0; e < 8; ++e) { h0[e] = (__bf16)x[e]; h1[e] = (__bf16)x[8 + e]; }
        size_t dst = ((size_t)(z * AHc + n0 + r)) * HIDC + k0 + cq * 16;
        *(bf16x8*)(Whi + dst)     = h0;
        *(bf16x8*)(Whi + dst + 8) = h1;
        return;
    }
    if (bid < 432) {
        // ---- pw_w convert (z=4, already [n][k]) ----
        int idx = (bid - 288) * 256 + tid;             // over AHc*HIDC/8
        size_t dst = (size_t)4 * AHc * HIDC + (size_t)idx * 8;
        *(bf16x8*)(Whi + dst) = cvt8(pww + (size_t)idx * 8);
        return;
    }
    if (bid < 440) {
        int idx = (bid - 432) * 256 + tid;
        if (idx < 5 * AHc) {
            int z = idx / AHc, n = idx % AHc;
            biasb[idx] = (z == 3) ? cob[n] : (z == 4) ? sepb[n] : 0.f;
        }
        return;
    }
    if (bid < 444) {
        // ---- td softmax, one block per batch ----
        int b = bid - 440;
        float* red = shmem;          // 256
        float* tv  = shmem + 256;    // 1024
        float ls = 0.f;
        for (int j = tid; j < Ss; j += 256) {
            float v = td[b * Ss + j];
            tv[j] = v;
            ls += v * v;
        }
        red[tid] = ls; __syncthreads();
        for (int s = 128; s > 0; s >>= 1) { if (tid < s) red[tid] += red[tid + s]; __syncthreads(); }
        float norm = fmaxf(sqrtf(red[0]), 1e-12f);
        __syncthreads();
        float lm = -3e38f;
        for (int j = tid; j < Ss; j += 256) {
            float v = mask[b * Ss + j] ? tv[j] / norm : -1e4f;
            tv[j] = v;
            lm = fmaxf(lm, v);
        }
        red[tid] = lm; __syncthreads();
        for (int s = 128; s > 0; s >>= 1) { if (tid < s) red[tid] = fmaxf(red[tid], red[tid + s]); __syncthreads(); }
        float m = red[0]; __syncthreads();
        float lsum = 0.f;
        for (int j = tid; j < Ss; j += 256) {
            float e = expf(tv[j] - m);
            tv[j] = e;
            lsum += e;
        }
        red[tid] = lsum; __syncthreads();
        for (int s = 128; s > 0; s >>= 1) { if (tid < s) red[tid] += red[tid + s]; __syncthreads(); }
        float inv = 1.f / red[0];
        __syncthreads();
        for (int j = tid; j < Ss; j += 256)
            td_sm[b * Ss + j] = tv[j] * inv;
        return;
    }
    {
        // ---- depthwise conv -> bf16 ----
        int idx = (bid - 444) * 256 + tid;             // over B*S*HID/4
        int c4 = idx % (HIDC / 4);
        int s  = (idx / (HIDC / 4)) % Ss;
        int b  = idx / ((HIDC / 4) * Ss);
        int c  = c4 * 4;
        float wv[4][KSc];
#pragma unroll
        for (int j = 0; j < 4; ++j)
#pragma unroll
            for (int k = 0; k < KSc; ++k) wv[j][k] = dww[(c + j) * KSc + k];
        float4 acc = {0.f, 0.f, 0.f, 0.f};
#pragma unroll
        for (int k = 0; k < KSc; ++k) {
            int sp = s + k - PADc;
            if (sp >= 0 && sp < Ss) {
                float4 v = *(const float4*)&Kin[(size_t)(b * Ss + sp) * HIDC + c];
                acc.x += v.x * wv[0][k]; acc.y += v.y * wv[1][k];
                acc.z += v.z * wv[2][k]; acc.w += v.w * wv[3][k];
            }
        }
        bf16x4 o = {(__bf16)acc.x, (__bf16)acc.y, (__bf16)acc.z, (__bf16)acc.w};
        *(bf16x4*)(dwbf + (size_t)idx * 4) = o;
    }
}

// ---------------- batched MFMA GEMM (single-term: ah*bh) ----------------
// A staged from f32 inputs directly (cvt8 + swizzled ds_write; Q/Kin/V for
// z=0/1/2,3) or gl_lds from dwbf (z=4). B via gl_lds, single-term bf16.
// Granule XOR swizzle s^(r&3) both sides. Fused epilogues: z=0 -> mq f32 + qh
// bf16; z=1 -> kh/kl bf16 (f32 accumulator split, 2-term K kept for attention);
// z=2 -> vt bf16 transposed; z=3/4 -> co/mkc f32 + bias.
__global__ __launch_bounds__(256) void k_gemm5(
        const float* __restrict__ Q, const float* __restrict__ Kin,
        const float* __restrict__ V, const __bf16* __restrict__ dwbf,
        const __bf16* __restrict__ Whi,
        const float* __restrict__ biasb, float* __restrict__ Call,
        __bf16* __restrict__ kh, __bf16* __restrict__ kl,
        __bf16* __restrict__ qh, __bf16* __restrict__ vt) {
    __shared__ __attribute__((aligned(16))) __bf16 As [128 * 32];
    __shared__ __attribute__((aligned(16))) __bf16 BsH[128 * 32];

    int wg = blockIdx.x + 3 * (blockIdx.y + 32 * blockIdx.z);   // 0..479
    int n2 = (wg & 7) * 60 + (wg >> 3);                         // bijective (480%8==0)
    int bxx = n2 % 3, byy = (n2 / 3) % 32, z = n2 / 96;

    int m0 = byy * 128, n0 = bxx * 128;
    int tid = threadIdx.x;
    int wave = tid >> 6, lane = tid & 63, quad = lane >> 4, l15 = lane & 15;

    int lrow = lane >> 2;                                // 0..15 within instr
    int lswz = 8 * ((lane & 3) ^ (lrow & 3));            // swizzled src granule offset

    // B staging (gl_lds): instr p = wave*2+q covers rows p*16..p*16+15
    int brow = wave * 32 + lrow;
    const __bf16* BhG0 = Whi + ((size_t)(z * AHc + n0 + brow)) * HIDC + lswz;
    const __bf16* BhG1 = BhG0 + (size_t)16 * HIDC;
    __bf16* BhL0 = BsH + (wave * 2 + 0) * 512;
    __bf16* BhL1 = BsH + (wave * 2 + 1) * 512;

    // A staging (gl_lds path, z == 4 only: dwbf already bf16)
    const __bf16* AG0 = dwbf + ((size_t)(m0 + wave * 32 + lrow)) * HIDC + lswz;
    const __bf16* AG1 = AG0 + (size_t)16 * HIDC;
    __bf16* AL0 = As + (wave * 2 + 0) * 512;
    __bf16* AL1 = As + (wave * 2 + 1) * 512;

    // A staging (f32 path, z != 4): swizzled ds_write of cvt'd granule pairs
    const float* Af32 = (z == 0) ? Q : (z == 1) ? Kin : V;
    int sr = tid >> 1;
    int sk = (tid & 1) * 16;
    const float* Arow = Af32 + (size_t)(m0 + sr) * HIDC + sk;
    int g0 = sk >> 3;                                    // 0 or 2
    int d0 = sr * 32 + ((g0       ^ (sr & 3)) * 8);
    int d1 = sr * 32 + (((g0 + 1) ^ (sr & 3)) * 8);

    int swz = (quad ^ (l15 & 3)) * 8;                    // swizzled read offset
    f32x4 acc[4][4] = {};

    for (int k0 = 0; k0 < HIDC; k0 += 32) {
        if (z == 4) {
            gl_lds16(AG0 + k0, AL0);
            gl_lds16(AG1 + k0, AL1);
        } else {
            const float* ap = Arow + k0;
            *(bf16x8*)&As[d0] = cvt8(ap);
            *(bf16x8*)&As[d1] = cvt8(ap + 8);
        }
        gl_lds16(BhG0 + k0, BhL0);
        gl_lds16(BhG1 + k0, BhL1);
        __syncthreads();

        int mrow = (wave >> 1) * 64 + l15;
        int nrow = (wave & 1) * 64 + l15;
        bf16x8 ah[4], bh[4];
#pragma unroll
        for (int mt = 0; mt < 4; ++mt)
            ah[mt] = *(bf16x8*)&As[(mrow + mt * 16) * 32 + swz];
#pragma unroll
        for (int nt = 0; nt < 4; ++nt)
            bh[nt] = *(bf16x8*)&BsH[(nrow + nt * 16) * 32 + swz];
#pragma unroll
        for (int mt = 0; mt < 4; ++mt)
#pragma unroll
            for (int nt = 0; nt < 4; ++nt)
                acc[mt][nt] = __builtin_amdgcn_mfma_f32_16x16x32_bf16(ah[mt], bh[nt], acc[mt][nt], 0, 0, 0);
        __syncthreads();
    }

    if (z == 1) {
        // zero bias; emit kh/kl bf16 directly (K used only by attention)
#pragma unroll
        for (int nt = 0; nt < 4; ++nt) {
            int n = n0 + (wave & 1) * 64 + nt * 16 + l15;
#pragma unroll
            for (int mt = 0; mt < 4; ++mt) {
#pragma unroll
                for (int r = 0; r < 4; ++r) {
                    int m = m0 + (wave >> 1) * 64 + mt * 16 + quad * 4 + r;
                    float v = acc[mt][nt][r];
                    __bf16 hv = (__bf16)v;
                    kh[(size_t)m * AHc + n] = hv;
                    kl[(size_t)m * AHc + n] = (__bf16)(v - (float)hv);
                }
            }
        }
    } else if (z == 2) {
        // zero bias; emit vt bf16 transposed directly: vt[(b*H+h)*D+d][s]
        int b = m0 >> 10;
#pragma unroll
        for (int nt = 0; nt < 4; ++nt) {
            int n = (wave & 1) * 64 + nt * 16 + l15;     // 0..127 within n0 tile
            int gn = n0 + n;                             // global col = h*64+d
            int h = gn >> 6, d = gn & 63;
#pragma unroll
            for (int mt = 0; mt < 4; ++mt) {
                int m = m0 + (wave >> 1) * 64 + mt * 16 + quad * 4;
                int s = m & (Ss - 1);
                bf16x4 o = {(__bf16)acc[mt][nt][0], (__bf16)acc[mt][nt][1],
                            (__bf16)acc[mt][nt][2], (__bf16)acc[mt][nt][3]};
                *(bf16x4*)&vt[((size_t)((b * Hh + h) * Dd + d)) * Ss + s] = o;
            }
        }
    } else if (z == 0) {
        // zero bias; write mq f32 (k_ckconv) + qh bf16 (attention)
#pragma unroll
        for (int nt = 0; nt < 4; ++nt) {
            int n = n0 + (wave & 1) * 64 + nt * 16 + l15;
#pragma unroll
            for (int mt = 0; mt < 4; ++mt) {
#pragma unroll
                for (int r = 0; r < 4; ++r) {
                    int m = m0 + (wave >> 1) * 64 + mt * 16 + quad * 4 + r;
                    float v = acc[mt][nt][r];
                    Call[(size_t)m * AHc + n] = v;
                    qh[(size_t)m * AHc + n] = (__bf16)v;
                }
            }
        }
    } else {
        float* Cz = Call + (size_t)z * MRr * AHc;
        const float* bz = biasb + z * AHc;
#pragma unroll
        for (int nt = 0; nt < 4; ++nt) {
            int n = n0 + (wave & 1) * 64 + nt * 16 + l15;
            float bias = bz[n];
#pragma unroll
            for (int mt = 0; mt < 4; ++mt) {
#pragma unroll
                for (int r = 0; r < 4; ++r) {
                    int m = m0 + (wave >> 1) * 64 + mt * 16 + quad * 4 + r;
                    Cz[(size_t)m * AHc + n] = acc[mt][nt][r] + bias;
                }
            }
        }
    }
}

// ============ fused ck linear + softmax + dynamic conv output ============
// Block = 4 rows (4 waves of 64). ckv stays in LDS; cksm buffer eliminated.
__global__ __launch_bounds__(256) void k_ckconv(const float* __restrict__ mkc,
                                                const float* __restrict__ mq,
                                                const float* __restrict__ ckW,
                                                const float* __restrict__ ckb,
                                                const float* __restrict__ co,
                                                float* __restrict__ out) {
    int tid = threadIdx.x;
    int lr = tid >> 6, lane = tid & 63;
    int row = blockIdx.x * 4 + lr;          // b*S + s
    __shared__ float ca[4][AHc];
    __shared__ float ckv[4][Hh * KSc];
    for (int o = lane; o < AHc; o += 64)
        ca[lr][o] = mkc[(size_t)row * AHc + o] * mq[(size_t)row * AHc + o];
    __syncthreads();
    if (lane < Hh * KSc) {
        float acc = ckb[lane];
        const float* wp = ckW + lane;
#pragma unroll 8
        for (int o = 0; o < AHc; ++o)
            acc += ca[lr][o] * wp[o * (Hh * KSc)];
        ckv[lr][lane] = acc;
    }
    __syncthreads();
    if (lane < Hh) {
        float m = -3e38f;
#pragma unroll
        for (int k = 0; k < KSc; ++k) m = fmaxf(m, ckv[lr][lane * KSc + k]);
        float e[KSc];
        float s = 0.f;
#pragma unroll
        for (int k = 0; k < KSc; ++k) { e[k] = expf(ckv[lr][lane * KSc + k] - m); s += e[k]; }
        float inv = 1.f / s;
#pragma unroll
        for (int k = 0; k < KSc; ++k) ckv[lr][lane * KSc + k] = e[k] * inv;
    }
    __syncthreads();
    // conv output for the block's 4 rows: 4 * 96 float4 items
#pragma unroll
    for (int e = 0; e < 2; ++e) {
        int it = e * 256 + tid;
        if (it >= 4 * (AHc / 4)) break;
        int r4i = it / (AHc / 4), dq = it % (AHc / 4);
        int h = dq >> 4, d4 = dq & 15;
        int row2 = blockIdx.x * 4 + r4i;
        int s = row2 & (Ss - 1), b = row2 >> 10;
        float4 acc = {0.f, 0.f, 0.f, 0.f};
#pragma unroll
        for (int k = 0; k < KSc; ++k) {
            int sp = s + k - PADc;
            if (sp >= 0 && sp < Ss) {
                float4 v = *(const float4*)&co[(size_t)(b * Ss + sp) * AHc + h * Dd + d4 * 4];
                float wv = ckv[r4i][h * KSc + k];
                acc.x += wv * v.x; acc.y += wv * v.y; acc.z += wv * v.z; acc.w += wv * v.w;
            }
        }
        *(float4*)&out[(size_t)row2 * (2 * AHc) + AHc + h * Dd + d4 * 4] = acc;
    }
}

// ---------------- attention: 16 q-rows/block, 512 threads, XCD-chunked remap ------
__device__ __forceinline__ int scix(int m, int j) {
    return m * 1024 + (j ^ (((m ^ (j >> 6)) & 7) << 2));
}

__global__ __attribute__((amdgpu_flat_work_group_size(512, 512), amdgpu_waves_per_eu(4, 4)))
void k_attn(const __bf16* __restrict__ qh,
            const __bf16* __restrict__ kh, const __bf16* __restrict__ kl,
            const __bf16* __restrict__ vt,
            const int* __restrict__ mask,
            const float* __restrict__ td_sm, const float* __restrict__ gammas,
            float* __restrict__ out) {
    __shared__ float sc[16 * 1024];      // 64 KB exactly
    int wg = blockIdx.x + 64 * blockIdx.y;
    int n  = (wg & 7) * 192 + (wg >> 3);
    int bx = n & 63, by = n >> 6;
    int i0 = bx * 16;
    int h = by % Hh, b = by / Hh;
    int tid = threadIdx.x;
    int w = tid >> 6, lane = tid & 63, quad = lane >> 4, l15 = lane & 15;
    int jw = w * 128;                     // this wave's j-range [jw, jw+128)

    // ---- phase 1: QK^T via MFMA: q_hi*(k_hi + k_lo) ----
    bf16x8 a_hi[2];
    {
        size_t qoff = (size_t)(b * Ss + i0 + l15) * AHc + h * Dd + quad * 8;
        a_hi[0] = *(const bf16x8*)(qh + qoff);
        a_hi[1] = *(const bf16x8*)(qh + qoff + 32);
    }
#pragma unroll 4
    for (int t = 0; t < 8; ++t) {
        int jt = jw + t * 16;
        size_t koff = (size_t)(b * Ss + jt + l15) * AHc + h * Dd + quad * 8;
        f32x4 acc = {0.f, 0.f, 0.f, 0.f};
#pragma unroll
        for (int kc = 0; kc < 2; ++kc) {
            bf16x8 khv = *(const bf16x8*)(kh + koff + kc * 32);
            bf16x8 klv = *(const bf16x8*)(kl + koff + kc * 32);
            acc = __builtin_amdgcn_mfma_f32_16x16x32_bf16(a_hi[kc], khv, acc, 0, 0, 0);
            acc = __builtin_amdgcn_mfma_f32_16x16x32_bf16(a_hi[kc], klv, acc, 0, 0, 0);
        }
#pragma unroll
        for (int r = 0; r < 4; ++r)
            sc[scix(quad * 4 + r, jt + l15)] = acc[r] * 0.125f;   // C: col=l15, row=quad*4+r
    }
    __syncthreads();

    // ---- phase 2: softmax -> cumsum -> decay -> softmax2 ----
    const float* tdrow = td_sm + b * Ss;
    float gamma = -log1pf(expf(gammas[h]));   // -softplus
    int jb = lane << 4;
    int mbits = 0;
    {
        const int4* mp = (const int4*)(mask + b * Ss + jb);
#pragma unroll
        for (int k = 0; k < 4; ++k) {
            int4 mv = mp[k];
            mbits |= (mv.x != 0) << (4 * k + 0);
            mbits |= (mv.y != 0) << (4 * k + 1);
            mbits |= (mv.z != 0) << (4 * k + 2);
            mbits |= (mv.w != 0) << (4 * k + 3);
        }
    }
    __attribute__((aligned(16))) float tdv[16];
    {
        const float4* tp = (const float4*)(tdrow + jb);
#pragma unroll
        for (int k = 0; k < 4; ++k) ((float4*)tdv)[k] = tp[k];
    }

    {
        int mA = w * 2, mB = mA + 1;
        int iA = i0 + mA, iB = i0 + mB;
        __attribute__((aligned(16))) float sA[16], sB[16];
        float pA[16], pB[16];
#pragma unroll
        for (int g = 0; g < 4; ++g) {
            *(f32x4*)(sA + 4 * g) = *(const f32x4*)&sc[scix(mA, jb + 4 * g)];
            *(f32x4*)(sB + 4 * g) = *(const f32x4*)&sc[scix(mB, jb + 4 * g)];
        }
#pragma unroll
        for (int jj = 0; jj < 16; ++jj) {
            if (!((mbits >> jj) & 1)) { sA[jj] = -1e30f; sB[jj] = -1e30f; }
        }
        float mxA = -1e30f, mxB = -1e30f;
#pragma unroll
        for (int jj = 0; jj < 16; ++jj) {
            mxA = fmaxf(mxA, sA[jj]);
            mxB = fmaxf(mxB, sB[jj]);
        }
#pragma unroll
        for (int d = 1; d < 64; d <<= 1) {
            mxA = fmaxf(mxA, __shfl_xor(mxA, d));
            mxB = fmaxf(mxB, __shfl_xor(mxB, d));
        }
#pragma unroll
        for (int jj = 0; jj < 16; ++jj) {
            pA[jj] = __expf(sA[jj] - mxA);     // masked -> exp(-inf) = 0
            pB[jj] = __expf(sB[jj] - mxB);
        }
#pragma unroll
        for (int jj = 1; jj < 16; ++jj) { pA[jj] += pA[jj - 1]; pB[jj] += pB[jj - 1]; }
        float tA = pA[15], tB = pB[15];
        float incA = tA, incB = tB;
#pragma unroll
        for (int dlt = 1; dlt < 64; dlt <<= 1) {
            float vA = __shfl_up(incA, dlt);
            float vB = __shfl_up(incB, dlt);
            if (lane >= dlt) { incA += vA; incB += vB; }
        }
        float offA = incA - tA, offB = incB - tB;
        float totA = __shfl(incA, 63), totB = __shfl(incB, 63);
        float invA = 1.f / fmaxf(totA, 1e-30f), invB = 1.f / fmaxf(totB, 1e-30f);
        float mx2A = -1e30f, mx2B = -1e30f;
#pragma unroll
        for (int jj = 0; jj < 16; ++jj) {
            int j = jb + jj;
            int bit = (mbits >> jj) & 1;
            float cumA = pA[jj] + offA, cumB = pB[jj] + offB;
            float posA = fabsf((float)(j - iA));
            float posB = fabsf((float)(j - iB));
            float dsA = sqrtf(fmaxf((totA - cumA) * invA * posA, 0.f));
            float dsB = sqrtf(fmaxf((totB - cumB) * invB * posB, 0.f));
            float teA = fminf(fmaxf(__expf(dsA * gamma), 1e-5f), 1e5f);
            float teB = fminf(fmaxf(__expf(dsB * gamma), 1e-5f), 1e5f);
            float tdj = tdv[jj];
            float multA = teA - ((j < iA) ? tdj : 0.f);
            float multB = teB - ((j < iB) ? tdj : 0.f);
            float s2A = bit ? sA[jj] * multA : -1e8f;
            float s2B = bit ? sB[jj] * multB : -1e8f;
            sA[jj] = s2A; sB[jj] = s2B;
            mx2A = fmaxf(mx2A, s2A); mx2B = fmaxf(mx2B, s2B);
        }
#pragma unroll
        for (int d = 1; d < 64; d <<= 1) {
            mx2A = fmaxf(mx2A, __shfl_xor(mx2A, d));
            mx2B = fmaxf(mx2B, __shfl_xor(mx2B, d));
        }
        float smA = 0.f, smB = 0.f;
#pragma unroll
        for (int jj = 0; jj < 16; ++jj) {
            sA[jj] = __expf(sA[jj] - mx2A); smA += sA[jj];
            sB[jj] = __expf(sB[jj] - mx2B); smB += sB[jj];
        }
#pragma unroll
        for (int d = 1; d < 64; d <<= 1) {
            smA += __shfl_xor(smA, d);
            smB += __shfl_xor(smB, d);
        }
        float i2A = 1.f / smA, i2B = 1.f / smB;
#pragma unroll
        for (int jj = 0; jj < 16; ++jj) { sA[jj] *= i2A; sB[jj] *= i2B; }
#pragma unroll
        for (int g = 0; g < 4; ++g) {
            *(f32x4*)&sc[scix(mA, jb + 4 * g)] = *(const f32x4*)(sA + 4 * g);
            *(f32x4*)&sc[scix(mB, jb + 4 * g)] = *(const f32x4*)(sB + 4 * g);
        }
    }
    __syncthreads();

    // ---- phase 3: PV via MFMA: (p_hi + p_lo) * v_hi; V pre-transposed bf16 [d][j] ----
    f32x4 oacc[4] = {};
    const __bf16* vtb = vt + (size_t)(b * Hh + h) * Dd * Ss;
#pragma unroll
    for (int kc = 0; kc < 4; ++kc) {
        int j0 = jw + kc * 32 + quad * 8;        // this lane's 8 j indices (k = quad*8+e)
        __attribute__((aligned(16))) float x[8];
        *(f32x4*)x       = *(const f32x4*)&sc[scix(l15, j0)];
        *(f32x4*)(x + 4) = *(const f32x4*)&sc[scix(l15, j0 + 4)];
        bf16x8 p_hi, p_lo;
        split8r(x, p_hi, p_lo);
#pragma unroll
        for (int nt = 0; nt < 4; ++nt) {
            int d = nt * 16 + l15;
            bf16x8 vv = *(const bf16x8*)(vtb + (size_t)d * Ss + j0);
            oacc[nt] = __builtin_amdgcn_mfma_f32_16x16x32_bf16(p_hi, vv, oacc[nt], 0, 0, 0);
            oacc[nt] = __builtin_amdgcn_mfma_f32_16x16x32_bf16(p_lo, vv, oacc[nt], 0, 0, 0);
        }
    }
    __syncthreads();                      // all waves done reading sc before reuse
#pragma unroll
    for (int nt = 0; nt < 4; ++nt)
#pragma unroll
        for (int r = 0; r < 4; ++r)
            sc[w * 1024 + (quad * 4 + r) * 64 + nt * 16 + l15] = oacc[nt][r];
    __syncthreads();
#pragma unroll
    for (int e = 0; e < 2; ++e) {
        int idx = e * 512 + tid;
        int m = idx >> 6, dd = idx & 63;
        float v = 0.f;
#pragma unroll
        for (int ww = 0; ww < 8; ++ww) v += sc[ww * 1024 + idx];
        out[(size_t)(b * Ss + i0 + m) * (2 * AHc) + h * Dd + dd] = v;
    }
}

extern "C" void kernel_launch(void* const* d_in, const int* in_sizes, int n_in,
                              void* d_out, int out_size, void* d_ws, size_t ws_size,
                              hipStream_t stream) {
    const float* Q    = (const float*)d_in[0];
    const float* Kin  = (const float*)d_in[1];
    const float* V    = (const float*)d_in[2];
    const float* td   = (const float*)d_in[3];
    const int*   mask = (const int*)d_in[4];
    const float* Wq   = (const float*)d_in[5];
    const float* Wk   = (const float*)d_in[6];
    const float* Wv   = (const float*)d_in[7];
    const float* dww  = (const float*)d_in[8];
    const float* pww  = (const float*)d_in[9];
    const float* sepb = (const float*)d_in[10];
    const float* ckW  = (const float*)d_in[11];
    const float* ckb  = (const float*)d_in[12];
    const float* coW  = (const float*)d_in[13];
    const float* cob  = (const float*)d_in[14];
    const float* gam  = (const float*)d_in[15];
    float* out = (float*)d_out;
    float* ws = (float*)d_ws;

    float* mq    = ws;                              // z=0 C (f32)
    float* mks   = mq    + (size_t)MRr * AHc;       // z=1 slot -> kh/kl bf16
    float* mvs   = mks   + (size_t)MRr * AHc;       // z=2 slot -> vt + qh bf16
    float* co    = mvs   + (size_t)MRr * AHc;       // z=3
    float* mkc   = co    + (size_t)MRr * AHc;       // z=4
    float* dwr   = mkc   + (size_t)MRr * AHc;       // MR*HID f32 region
    float* tdsm  = dwr   + (size_t)MRr * HIDC;      // B*S
    float* biasb = tdsm  + (size_t)Bb * Ss;         // 5*384

    // dwr region: depthwise bf16 output (dead after k_gemm5)
    __bf16* dwbf = (__bf16*)dwr;
    // attention operands live in dedicated ws slots (no aliasing with gemm inputs):
    __bf16* kh = (__bf16*)mks;                      // z=1 epilogue output
    __bf16* kl = kh + (size_t)MRr * AHc;
    __bf16* vt = (__bf16*)mvs;                      // z=2 epilogue output (transposed V)
    __bf16* qh = vt + (size_t)MRr * AHc;            // z=0 epilogue output

    // d_out scratch: Whi (2.95 MB) — dead after k_gemm5
    __bf16* Whi = (__bf16*)d_out;

    k_pre<<<3516, 256, 0, stream>>>(Wq, Wk, Wv, coW, pww, cob, sepb, td, mask,
                                    Kin, dww, Whi, biasb, tdsm, dwbf);

    dim3 gg(AHc / 128, MRr / 128, 5);   // 3 x 32 x 5
    k_gemm5<<<gg, 256, 0, stream>>>(Q, Kin, V, dwbf, Whi, biasb, mq, kh, kl, qh, vt);

    k_ckconv<<<MRr / 4, 256, 0, stream>>>(mkc, mq, ckW, ckb, co, out);

    dim3 ga(64, 24);                    // 1536 blocks
    k_attn<<<ga, 512, 0, stream>>>(qh, kh, kl, vt, mask, tdsm, gam, out);
}

// Round 14
// 267.940 us; speedup vs baseline: 1.0196x; 1.0196x over previous
//
#include <hip/hip_runtime.h>
#include <hip/hip_bf16.h>

#define HIDC 768
#define Hh   6
#define Dd   64
#define AHc  384
#define KSc  9
#define PADc 4
#define Bb   4
#define Ss   1024
#define MRr  (Bb * Ss)          // 4096

typedef __attribute__((ext_vector_type(8))) __bf16 bf16x8;
typedef __attribute__((ext_vector_type(4))) __bf16 bf16x4;
typedef __attribute__((ext_vector_type(4))) float  f32x4;

// async global->LDS, 16 bytes per lane; dest = wave-uniform base + lane*16
__device__ __forceinline__ void gl_lds16(const void* g, void* l) {
    __builtin_amdgcn_global_load_lds(
        (const __attribute__((address_space(1))) void*)g,
        (__attribute__((address_space(3))) void*)l, 16, 0, 0);
}

// split 8 consecutive f32 into hi/lo bf16 fragments
__device__ __forceinline__ void split8r(const float* xs, bf16x8& hi, bf16x8& lo) {
#pragma unroll
    for (int e = 0; e < 8; ++e) {
        __bf16 hv = (__bf16)xs[e];
        hi[e] = hv;
        lo[e] = (__bf16)(xs[e] - (float)hv);
    }
}

// convert 8 consecutive f32 to bf16 (hi only)
__device__ __forceinline__ bf16x8 cvt8(const float* p) {
    float4 x0 = *(const float4*)p;
    float4 x1 = *(const float4*)(p + 4);
    float xs[8] = {x0.x, x0.y, x0.z, x0.w, x1.x, x1.y, x1.z, x1.w};
    bf16x8 h;
#pragma unroll
    for (int e = 0; e < 8; ++e) h[e] = (__bf16)xs[e];
    return h;
}

// ============ fused preprocessing: wsplit_t + pw cvt + bias + td + dw + absplit ====
// blocks [0,288): wsplit_t; [288,432): pw cvt; [432,440): bias; [440,444): td;
// [444, 444+6144): depthwise (3072) + absplit (3072)
// Weights are single-term bf16 (hi only) — see k_gemm5 note.
__global__ __launch_bounds__(256) void k_pre(
        const float* __restrict__ Wq, const float* __restrict__ Wk,
        const float* __restrict__ Wv, const float* __restrict__ coW,
        const float* __restrict__ pww, const float* __restrict__ cob,
        const float* __restrict__ sepb, const float* __restrict__ td,
        const int* __restrict__ mask, const float* __restrict__ Kin,
        const float* __restrict__ dww, const float* __restrict__ Q,
        const float* __restrict__ V,
        __bf16* __restrict__ Whi,
        float* __restrict__ biasb, float* __restrict__ td_sm,
        __bf16* __restrict__ dwbf, __bf16* __restrict__ qbf,
        __bf16* __restrict__ vbf) {
    __shared__ float shmem[64 * 65];
    int bid = blockIdx.x;
    int tid = threadIdx.x;
    if (bid < 288) {
        // ---- transposed weight convert ----
        int z = bid / 72, rem = bid % 72;
        int n0 = (rem % 6) * 64, k0 = (rem / 6) * 64;
        const float* src = (z == 0) ? Wq : (z == 1) ? Wk : (z == 2) ? Wv : coW;
        float (*tile)[65] = (float(*)[65])shmem;
        int r = tid >> 2, cq = tid & 3;
#pragma unroll
        for (int e = 0; e < 4; ++e) {
            float4 v = *(const float4*)&src[(size_t)(k0 + r) * AHc + n0 + cq * 16 + e * 4];
            tile[r][cq * 16 + e * 4 + 0] = v.x;
            tile[r][cq * 16 + e * 4 + 1] = v.y;
            tile[r][cq * 16 + e * 4 + 2] = v.z;
            tile[r][cq * 16 + e * 4 + 3] = v.w;
        }
        __syncthreads();
        float x[16];
#pragma unroll
        for (int e = 0; e < 16; ++e) x[e] = tile[cq * 16 + e][r];
        bf16x8 h0, h1;
#pragma unroll
        for (int e = 0; e < 8; ++e) { h0[e] = (__bf16)x[e]; h1[e] = (__bf16)x[8 + e]; }
        size_t dst = ((size_t)(z * AHc + n0 + r)) * HIDC + k0 + cq * 16;
        *(bf16x8*)(Whi + dst)     = h0;
        *(bf16x8*)(Whi + dst + 8) = h1;
        return;
    }
    if (bid < 432) {
        // ---- pw_w convert (z=4, already [n][k]) ----
        int idx = (bid - 288) * 256 + tid;             // over AHc*HIDC/8
        size_t dst = (size_t)4 * AHc * HIDC + (size_t)idx * 8;
        *(bf16x8*)(Whi + dst) = cvt8(pww + (size_t)idx * 8);
        return;
    }
    if (bid < 440) {
        int idx = (bid - 432) * 256 + tid;
        if (idx < 5 * AHc) {
            int z = idx / AHc, n = idx % AHc;
            biasb[idx] = (z == 3) ? cob[n] : (z == 4) ? sepb[n] : 0.f;
        }
        return;
    }
    if (bid < 444) {
        // ---- td softmax, one block per batch ----
        int b = bid - 440;
        float* red = shmem;          // 256
        float* tv  = shmem + 256;    // 1024
        float ls = 0.f;
        for (int j = tid; j < Ss; j += 256) {
            float v = td[b * Ss + j];
            tv[j] = v;
            ls += v * v;
        }
        red[tid] = ls; __syncthreads();
        for (int s = 128; s > 0; s >>= 1) { if (tid < s) red[tid] += red[tid + s]; __syncthreads(); }
        float norm = fmaxf(sqrtf(red[0]), 1e-12f);
        __syncthreads();
        float lm = -3e38f;
        for (int j = tid; j < Ss; j += 256) {
            float v = mask[b * Ss + j] ? tv[j] / norm : -1e4f;
            tv[j] = v;
            lm = fmaxf(lm, v);
        }
        red[tid] = lm; __syncthreads();
        for (int s = 128; s > 0; s >>= 1) { if (tid < s) red[tid] = fmaxf(red[tid], red[tid + s]); __syncthreads(); }
        float m = red[0]; __syncthreads();
        float lsum = 0.f;
        for (int j = tid; j < Ss; j += 256) {
            float e = expf(tv[j] - m);
            tv[j] = e;
            lsum += e;
        }
        red[tid] = lsum; __syncthreads();
        for (int s = 128; s > 0; s >>= 1) { if (tid < s) red[tid] += red[tid + s]; __syncthreads(); }
        float inv = 1.f / red[0];
        __syncthreads();
        for (int j = tid; j < Ss; j += 256)
            td_sm[b * Ss + j] = tv[j] * inv;
        return;
    }
    int db = bid - 444;
    if (db < 3072) {
        // ---- depthwise conv -> bf16 ----
        int idx = db * 256 + tid;                      // over B*S*HID/4
        int c4 = idx % (HIDC / 4);
        int s  = (idx / (HIDC / 4)) % Ss;
        int b  = idx / ((HIDC / 4) * Ss);
        int c  = c4 * 4;
        float wv[4][KSc];
#pragma unroll
        for (int j = 0; j < 4; ++j)
#pragma unroll
            for (int k = 0; k < KSc; ++k) wv[j][k] = dww[(c + j) * KSc + k];
        float4 acc = {0.f, 0.f, 0.f, 0.f};
#pragma unroll
        for (int k = 0; k < KSc; ++k) {
            int sp = s + k - PADc;
            if (sp >= 0 && sp < Ss) {
                float4 v = *(const float4*)&Kin[(size_t)(b * Ss + sp) * HIDC + c];
                acc.x += v.x * wv[0][k]; acc.y += v.y * wv[1][k];
                acc.z += v.z * wv[2][k]; acc.w += v.w * wv[3][k];
            }
        }
        bf16x4 o = {(__bf16)acc.x, (__bf16)acc.y, (__bf16)acc.z, (__bf16)acc.w};
        *(bf16x4*)(dwbf + (size_t)idx * 4) = o;
    } else {
        // ---- Q/V pre-convert ----
        const int n8 = MRr * HIDC / 8;
        int idx = (db - 3072) * 256 + tid;             // over 2 * MR*HID/8
        if (idx < n8) {
            *(bf16x8*)(qbf + (size_t)idx * 8) = cvt8(Q + (size_t)idx * 8);
        } else {
            int i = idx - n8;
            *(bf16x8*)(vbf + (size_t)i * 8) = cvt8(V + (size_t)i * 8);
        }
    }
}

// ---------------- batched MFMA GEMM (single-term: ah*bh) ----------------
// Weights single-term bf16 (A operands already hi-only bf16; absmax threshold
// has 5x headroom). LDS 16 KB -> high occupancy. Granule XOR swizzle s^(r&3)
// both sides. Fused epilogues: z=0 -> mq f32 + qh bf16; z=1 -> kh/kl bf16
// (f32 accumulator split, 2-term K kept for attention); z=2 -> vt bf16
// transposed; z=3/4 -> co/mkc f32 + bias.
__global__ __launch_bounds__(256) void k_gemm5(
        const __bf16* __restrict__ qbf, const float* __restrict__ Kin,
        const __bf16* __restrict__ vbf, const __bf16* __restrict__ dwbf,
        const __bf16* __restrict__ Whi,
        const float* __restrict__ biasb, float* __restrict__ Call,
        __bf16* __restrict__ kh, __bf16* __restrict__ kl,
        __bf16* __restrict__ qh, __bf16* __restrict__ vt) {
    __shared__ __attribute__((aligned(16))) __bf16 As [128 * 32];
    __shared__ __attribute__((aligned(16))) __bf16 BsH[128 * 32];

    int wg = blockIdx.x + 3 * (blockIdx.y + 32 * blockIdx.z);   // 0..479
    int n2 = (wg & 7) * 60 + (wg >> 3);                         // bijective (480%8==0)
    int bxx = n2 % 3, byy = (n2 / 3) % 32, z = n2 / 96;

    int m0 = byy * 128, n0 = bxx * 128;
    int tid = threadIdx.x;
    int wave = tid >> 6, lane = tid & 63, quad = lane >> 4, l15 = lane & 15;

    int lrow = lane >> 2;                                // 0..15 within instr
    int lswz = 8 * ((lane & 3) ^ (lrow & 3));            // swizzled src granule offset

    // B staging (gl_lds): instr p = wave*2+q covers rows p*16..p*16+15
    int brow = wave * 32 + lrow;
    const __bf16* BhG0 = Whi + ((size_t)(z * AHc + n0 + brow)) * HIDC + lswz;
    const __bf16* BhG1 = BhG0 + (size_t)16 * HIDC;
    __bf16* BhL0 = BsH + (wave * 2 + 0) * 512;
    __bf16* BhL1 = BsH + (wave * 2 + 1) * 512;

    // A staging (gl_lds path, z != 1)
    const __bf16* Abf = (z == 0) ? qbf : (z == 4) ? dwbf : vbf;
    const __bf16* AG0 = Abf + ((size_t)(m0 + wave * 32 + lrow)) * HIDC + lswz;
    const __bf16* AG1 = AG0 + (size_t)16 * HIDC;
    __bf16* AL0 = As + (wave * 2 + 0) * 512;
    __bf16* AL1 = As + (wave * 2 + 1) * 512;

    // A staging (f32 path, z == 1): swizzled ds_write of cvt'd granule pairs
    int sr = tid >> 1;
    int sk = (tid & 1) * 16;
    const float* Arow = Kin + (size_t)(m0 + sr) * HIDC + sk;
    int g0 = sk >> 3;                                    // 0 or 2
    int d0 = sr * 32 + ((g0       ^ (sr & 3)) * 8);
    int d1 = sr * 32 + (((g0 + 1) ^ (sr & 3)) * 8);

    int swz = (quad ^ (l15 & 3)) * 8;                    // swizzled read offset
    f32x4 acc[4][4] = {};

    for (int k0 = 0; k0 < HIDC; k0 += 32) {
        if (z == 1) {
            const float* ap = Arow + k0;
            *(bf16x8*)&As[d0] = cvt8(ap);
            *(bf16x8*)&As[d1] = cvt8(ap + 8);
        } else {
            gl_lds16(AG0 + k0, AL0);
            gl_lds16(AG1 + k0, AL1);
        }
        gl_lds16(BhG0 + k0, BhL0);
        gl_lds16(BhG1 + k0, BhL1);
        __syncthreads();

        int mrow = (wave >> 1) * 64 + l15;
        int nrow = (wave & 1) * 64 + l15;
        bf16x8 ah[4], bh[4];
#pragma unroll
        for (int mt = 0; mt < 4; ++mt)
            ah[mt] = *(bf16x8*)&As[(mrow + mt * 16) * 32 + swz];
#pragma unroll
        for (int nt = 0; nt < 4; ++nt)
            bh[nt] = *(bf16x8*)&BsH[(nrow + nt * 16) * 32 + swz];
#pragma unroll
        for (int mt = 0; mt < 4; ++mt)
#pragma unroll
            for (int nt = 0; nt < 4; ++nt)
                acc[mt][nt] = __builtin_amdgcn_mfma_f32_16x16x32_bf16(ah[mt], bh[nt], acc[mt][nt], 0, 0, 0);
        __syncthreads();
    }

    if (z == 1) {
        // zero bias; emit kh/kl bf16 directly (K used only by attention)
#pragma unroll
        for (int nt = 0; nt < 4; ++nt) {
            int n = n0 + (wave & 1) * 64 + nt * 16 + l15;
#pragma unroll
            for (int mt = 0; mt < 4; ++mt) {
#pragma unroll
                for (int r = 0; r < 4; ++r) {
                    int m = m0 + (wave >> 1) * 64 + mt * 16 + quad * 4 + r;
                    float v = acc[mt][nt][r];
                    __bf16 hv = (__bf16)v;
                    kh[(size_t)m * AHc + n] = hv;
                    kl[(size_t)m * AHc + n] = (__bf16)(v - (float)hv);
                }
            }
        }
    } else if (z == 2) {
        // zero bias; emit vt bf16 transposed directly: vt[(b*H+h)*D+d][s]
        int b = m0 >> 10;
#pragma unroll
        for (int nt = 0; nt < 4; ++nt) {
            int n = (wave & 1) * 64 + nt * 16 + l15;     // 0..127 within n0 tile
            int gn = n0 + n;                             // global col = h*64+d
            int h = gn >> 6, d = gn & 63;
#pragma unroll
            for (int mt = 0; mt < 4; ++mt) {
                int m = m0 + (wave >> 1) * 64 + mt * 16 + quad * 4;
                int s = m & (Ss - 1);
                bf16x4 o = {(__bf16)acc[mt][nt][0], (__bf16)acc[mt][nt][1],
                            (__bf16)acc[mt][nt][2], (__bf16)acc[mt][nt][3]};
                *(bf16x4*)&vt[((size_t)((b * Hh + h) * Dd + d)) * Ss + s] = o;
            }
        }
    } else if (z == 0) {
        // zero bias; write mq f32 (k_ckconv) + qh bf16 (attention)
#pragma unroll
        for (int nt = 0; nt < 4; ++nt) {
            int n = n0 + (wave & 1) * 64 + nt * 16 + l15;
#pragma unroll
            for (int mt = 0; mt < 4; ++mt) {
#pragma unroll
                for (int r = 0; r < 4; ++r) {
                    int m = m0 + (wave >> 1) * 64 + mt * 16 + quad * 4 + r;
                    float v = acc[mt][nt][r];
                    Call[(size_t)m * AHc + n] = v;
                    qh[(size_t)m * AHc + n] = (__bf16)v;
                }
            }
        }
    } else {
        float* Cz = Call + (size_t)z * MRr * AHc;
        const float* bz = biasb + z * AHc;
#pragma unroll
        for (int nt = 0; nt < 4; ++nt) {
            int n = n0 + (wave & 1) * 64 + nt * 16 + l15;
            float bias = bz[n];
#pragma unroll
            for (int mt = 0; mt < 4; ++mt) {
#pragma unroll
                for (int r = 0; r < 4; ++r) {
                    int m = m0 + (wave >> 1) * 64 + mt * 16 + quad * 4 + r;
                    Cz[(size_t)m * AHc + n] = acc[mt][nt][r] + bias;
                }
            }
        }
    }
}

// ============ fused ck linear + softmax + dynamic conv output ============
// Block = 4 rows (4 waves of 64). ckv stays in LDS; cksm buffer eliminated.
__global__ __launch_bounds__(256) void k_ckconv(const float* __restrict__ mkc,
                                                const float* __restrict__ mq,
                                                const float* __restrict__ ckW,
                                                const float* __restrict__ ckb,
                                                const float* __restrict__ co,
                                                float* __restrict__ out) {
    int tid = threadIdx.x;
    int lr = tid >> 6, lane = tid & 63;
    int row = blockIdx.x * 4 + lr;          // b*S + s
    __shared__ float ca[4][AHc];
    __shared__ float ckv[4][Hh * KSc];
    for (int o = lane; o < AHc; o += 64)
        ca[lr][o] = mkc[(size_t)row * AHc + o] * mq[(size_t)row * AHc + o];
    __syncthreads();
    if (lane < Hh * KSc) {
        float acc = ckb[lane];
        const float* wp = ckW + lane;
#pragma unroll 8
        for (int o = 0; o < AHc; ++o)
            acc += ca[lr][o] * wp[o * (Hh * KSc)];
        ckv[lr][lane] = acc;
    }
    __syncthreads();
    if (lane < Hh) {
        float m = -3e38f;
#pragma unroll
        for (int k = 0; k < KSc; ++k) m = fmaxf(m, ckv[lr][lane * KSc + k]);
        float e[KSc];
        float s = 0.f;
#pragma unroll
        for (int k = 0; k < KSc; ++k) { e[k] = expf(ckv[lr][lane * KSc + k] - m); s += e[k]; }
        float inv = 1.f / s;
#pragma unroll
        for (int k = 0; k < KSc; ++k) ckv[lr][lane * KSc + k] = e[k] * inv;
    }
    __syncthreads();
    // conv output for the block's 4 rows: 4 * 96 float4 items
#pragma unroll
    for (int e = 0; e < 2; ++e) {
        int it = e * 256 + tid;
        if (it >= 4 * (AHc / 4)) break;
        int r4i = it / (AHc / 4), dq = it % (AHc / 4);
        int h = dq >> 4, d4 = dq & 15;
        int row2 = blockIdx.x * 4 + r4i;
        int s = row2 & (Ss - 1), b = row2 >> 10;
        float4 acc = {0.f, 0.f, 0.f, 0.f};
#pragma unroll
        for (int k = 0; k < KSc; ++k) {
            int sp = s + k - PADc;
            if (sp >= 0 && sp < Ss) {
                float4 v = *(const float4*)&co[(size_t)(b * Ss + sp) * AHc + h * Dd + d4 * 4];
                float wv = ckv[r4i][h * KSc + k];
                acc.x += wv * v.x; acc.y += wv * v.y; acc.z += wv * v.z; acc.w += wv * v.w;
            }
        }
        *(float4*)&out[(size_t)row2 * (2 * AHc) + AHc + h * Dd + d4 * 4] = acc;
    }
}

// ---------------- attention: 16 q-rows/block, 512 threads, XCD-chunked remap ------
__device__ __forceinline__ int scix(int m, int j) {
    return m * 1024 + (j ^ (((m ^ (j >> 6)) & 7) << 2));
}

__global__ __attribute__((amdgpu_flat_work_group_size(512, 512), amdgpu_waves_per_eu(4, 4)))
void k_attn(const __bf16* __restrict__ qh,
            const __bf16* __restrict__ kh, const __bf16* __restrict__ kl,
            const __bf16* __restrict__ vt,
            const int* __restrict__ mask,
            const float* __restrict__ td_sm, const float* __restrict__ gammas,
            float* __restrict__ out) {
    __shared__ float sc[16 * 1024];      // 64 KB exactly
    int wg = blockIdx.x + 64 * blockIdx.y;
    int n  = (wg & 7) * 192 + (wg >> 3);
    int bx = n & 63, by = n >> 6;
    int i0 = bx * 16;
    int h = by % Hh, b = by / Hh;
    int tid = threadIdx.x;
    int w = tid >> 6, lane = tid & 63, quad = lane >> 4, l15 = lane & 15;
    int jw = w * 128;                     // this wave's j-range [jw, jw+128)

    // ---- phase 1: QK^T via MFMA: q_hi*(k_hi + k_lo) ----
    bf16x8 a_hi[2];
    {
        size_t qoff = (size_t)(b * Ss + i0 + l15) * AHc + h * Dd + quad * 8;
        a_hi[0] = *(const bf16x8*)(qh + qoff);
        a_hi[1] = *(const bf16x8*)(qh + qoff + 32);
    }
#pragma unroll 4
    for (int t = 0; t < 8; ++t) {
        int jt = jw + t * 16;
        size_t koff = (size_t)(b * Ss + jt + l15) * AHc + h * Dd + quad * 8;
        f32x4 acc = {0.f, 0.f, 0.f, 0.f};
#pragma unroll
        for (int kc = 0; kc < 2; ++kc) {
            bf16x8 khv = *(const bf16x8*)(kh + koff + kc * 32);
            bf16x8 klv = *(const bf16x8*)(kl + koff + kc * 32);
            acc = __builtin_amdgcn_mfma_f32_16x16x32_bf16(a_hi[kc], khv, acc, 0, 0, 0);
            acc = __builtin_amdgcn_mfma_f32_16x16x32_bf16(a_hi[kc], klv, acc, 0, 0, 0);
        }
#pragma unroll
        for (int r = 0; r < 4; ++r)
            sc[scix(quad * 4 + r, jt + l15)] = acc[r] * 0.125f;   // C: col=l15, row=quad*4+r
    }
    __syncthreads();

    // ---- phase 2: softmax -> cumsum -> decay -> softmax2 ----
    const float* tdrow = td_sm + b * Ss;
    float gamma = -log1pf(expf(gammas[h]));   // -softplus
    int jb = lane << 4;
    int mbits = 0;
    {
        const int4* mp = (const int4*)(mask + b * Ss + jb);
#pragma unroll
        for (int k = 0; k < 4; ++k) {
            int4 mv = mp[k];
            mbits |= (mv.x != 0) << (4 * k + 0);
            mbits |= (mv.y != 0) << (4 * k + 1);
            mbits |= (mv.z != 0) << (4 * k + 2);
            mbits |= (mv.w != 0) << (4 * k + 3);
        }
    }
    __attribute__((aligned(16))) float tdv[16];
    {
        const float4* tp = (const float4*)(tdrow + jb);
#pragma unroll
        for (int k = 0; k < 4; ++k) ((float4*)tdv)[k] = tp[k];
    }

    {
        int mA = w * 2, mB = mA + 1;
        int iA = i0 + mA, iB = i0 + mB;
        __attribute__((aligned(16))) float sA[16], sB[16];
        float pA[16], pB[16];
#pragma unroll
        for (int g = 0; g < 4; ++g) {
            *(f32x4*)(sA + 4 * g) = *(const f32x4*)&sc[scix(mA, jb + 4 * g)];
            *(f32x4*)(sB + 4 * g) = *(const f32x4*)&sc[scix(mB, jb + 4 * g)];
        }
#pragma unroll
        for (int jj = 0; jj < 16; ++jj) {
            if (!((mbits >> jj) & 1)) { sA[jj] = -1e30f; sB[jj] = -1e30f; }
        }
        float mxA = -1e30f, mxB = -1e30f;
#pragma unroll
        for (int jj = 0; jj < 16; ++jj) {
            mxA = fmaxf(mxA, sA[jj]);
            mxB = fmaxf(mxB, sB[jj]);
        }
#pragma unroll
        for (int d = 1; d < 64; d <<= 1) {
            mxA = fmaxf(mxA, __shfl_xor(mxA, d));
            mxB = fmaxf(mxB, __shfl_xor(mxB, d));
        }
#pragma unroll
        for (int jj = 0; jj < 16; ++jj) {
            pA[jj] = __expf(sA[jj] - mxA);     // masked -> exp(-inf) = 0
            pB[jj] = __expf(sB[jj] - mxB);
        }
#pragma unroll
        for (int jj = 1; jj < 16; ++jj) { pA[jj] += pA[jj - 1]; pB[jj] += pB[jj - 1]; }
        float tA = pA[15], tB = pB[15];
        float incA = tA, incB = tB;
#pragma unroll
        for (int dlt = 1; dlt < 64; dlt <<= 1) {
            float vA = __shfl_up(incA, dlt);
            float vB = __shfl_up(incB, dlt);
            if (lane >= dlt) { incA += vA; incB += vB; }
        }
        float offA = incA - tA, offB = incB - tB;
        float totA = __shfl(incA, 63), totB = __shfl(incB, 63);
        float invA = 1.f / fmaxf(totA, 1e-30f), invB = 1.f / fmaxf(totB, 1e-30f);
        float mx2A = -1e30f, mx2B = -1e30f;
#pragma unroll
        for (int jj = 0; jj < 16; ++jj) {
            int j = jb + jj;
            int bit = (mbits >> jj) & 1;
            float cumA = pA[jj] + offA, cumB = pB[jj] + offB;
            float posA = fabsf((float)(j - iA));
            float posB = fabsf((float)(j - iB));
            float dsA = sqrtf(fmaxf((totA - cumA) * invA * posA, 0.f));
            float dsB = sqrtf(fmaxf((totB - cumB) * invB * posB, 0.f));
            float teA = fminf(fmaxf(__expf(dsA * gamma), 1e-5f), 1e5f);
            float teB = fminf(fmaxf(__expf(dsB * gamma), 1e-5f), 1e5f);
            float tdj = tdv[jj];
            float multA = teA - ((j < iA) ? tdj : 0.f);
            float multB = teB - ((j < iB) ? tdj : 0.f);
            float s2A = bit ? sA[jj] * multA : -1e8f;
            float s2B = bit ? sB[jj] * multB : -1e8f;
            sA[jj] = s2A; sB[jj] = s2B;
            mx2A = fmaxf(mx2A, s2A); mx2B = fmaxf(mx2B, s2B);
        }
#pragma unroll
        for (int d = 1; d < 64; d <<= 1) {
            mx2A = fmaxf(mx2A, __shfl_xor(mx2A, d));
            mx2B = fmaxf(mx2B, __shfl_xor(mx2B, d));
        }
        float smA = 0.f, smB = 0.f;
#pragma unroll
        for (int jj = 0; jj < 16; ++jj) {
            sA[jj] = __expf(sA[jj] - mx2A); smA += sA[jj];
            sB[jj] = __expf(sB[jj] - mx2B); smB += sB[jj];
        }
#pragma unroll
        for (int d = 1; d < 64; d <<= 1) {
            smA += __shfl_xor(smA, d);
            smB += __shfl_xor(smB, d);
        }
        float i2A = 1.f / smA, i2B = 1.f / smB;
#pragma unroll
        for (int jj = 0; jj < 16; ++jj) { sA[jj] *= i2A; sB[jj] *= i2B; }
#pragma unroll
        for (int g = 0; g < 4; ++g) {
            *(f32x4*)&sc[scix(mA, jb + 4 * g)] = *(const f32x4*)(sA + 4 * g);
            *(f32x4*)&sc[scix(mB, jb + 4 * g)] = *(const f32x4*)(sB + 4 * g);
        }
    }
    __syncthreads();

    // ---- phase 3: PV via MFMA: (p_hi + p_lo) * v_hi; V pre-transposed bf16 [d][j] ----
    f32x4 oacc[4] = {};
    const __bf16* vtb = vt + (size_t)(b * Hh + h) * Dd * Ss;
#pragma unroll
    for (int kc = 0; kc < 4; ++kc) {
        int j0 = jw + kc * 32 + quad * 8;        // this lane's 8 j indices (k = quad*8+e)
        __attribute__((aligned(16))) float x[8];
        *(f32x4*)x       = *(const f32x4*)&sc[scix(l15, j0)];
        *(f32x4*)(x + 4) = *(const f32x4*)&sc[scix(l15, j0 + 4)];
        bf16x8 p_hi, p_lo;
        split8r(x, p_hi, p_lo);
#pragma unroll
        for (int nt = 0; nt < 4; ++nt) {
            int d = nt * 16 + l15;
            bf16x8 vv = *(const bf16x8*)(vtb + (size_t)d * Ss + j0);
            oacc[nt] = __builtin_amdgcn_mfma_f32_16x16x32_bf16(p_hi, vv, oacc[nt], 0, 0, 0);
            oacc[nt] = __builtin_amdgcn_mfma_f32_16x16x32_bf16(p_lo, vv, oacc[nt], 0, 0, 0);
        }
    }
    __syncthreads();                      // all waves done reading sc before reuse
#pragma unroll
    for (int nt = 0; nt < 4; ++nt)
#pragma unroll
        for (int r = 0; r < 4; ++r)
            sc[w * 1024 + (quad * 4 + r) * 64 + nt * 16 + l15] = oacc[nt][r];
    __syncthreads();
#pragma unroll
    for (int e = 0; e < 2; ++e) {
        int idx = e * 512 + tid;
        int m = idx >> 6, dd = idx & 63;
        float v = 0.f;
#pragma unroll
        for (int ww = 0; ww < 8; ++ww) v += sc[ww * 1024 + idx];
        out[(size_t)(b * Ss + i0 + m) * (2 * AHc) + h * Dd + dd] = v;
    }
}

extern "C" void kernel_launch(void* const* d_in, const int* in_sizes, int n_in,
                              void* d_out, int out_size, void* d_ws, size_t ws_size,
                              hipStream_t stream) {
    const float* Q    = (const float*)d_in[0];
    const float* Kin  = (const float*)d_in[1];
    const float* V    = (const float*)d_in[2];
    const float* td   = (const float*)d_in[3];
    const int*   mask = (const int*)d_in[4];
    const float* Wq   = (const float*)d_in[5];
    const float* Wk   = (const float*)d_in[6];
    const float* Wv   = (const float*)d_in[7];
    const float* dww  = (const float*)d_in[8];
    const float* pww  = (const float*)d_in[9];
    const float* sepb = (const float*)d_in[10];
    const float* ckW  = (const float*)d_in[11];
    const float* ckb  = (const float*)d_in[12];
    const float* coW  = (const float*)d_in[13];
    const float* cob  = (const float*)d_in[14];
    const float* gam  = (const float*)d_in[15];
    float* out = (float*)d_out;
    float* ws = (float*)d_ws;

    float* mq    = ws;                              // z=0 C (f32)
    float* mks   = mq    + (size_t)MRr * AHc;       // z=1 slot -> kh/kl bf16
    float* mvs   = mks   + (size_t)MRr * AHc;       // z=2 slot -> vt + qh bf16
    float* co    = mvs   + (size_t)MRr * AHc;       // z=3
    float* mkc   = co    + (size_t)MRr * AHc;       // z=4
    float* dwr   = mkc   + (size_t)MRr * AHc;       // MR*HID f32 region
    float* tdsm  = dwr   + (size_t)MRr * HIDC;      // B*S
    float* biasb = tdsm  + (size_t)Bb * Ss;         // 5*384

    // dwr region: pre-gemm staging [dwbf | qbf] bf16 (dead after k_gemm5)
    __bf16* dwbf = (__bf16*)dwr;
    __bf16* qbf  = (__bf16*)(dwr + (size_t)MRr * HIDC / 2);
    // attention operands live in dedicated ws slots (no aliasing with gemm inputs):
    __bf16* kh = (__bf16*)mks;                      // z=1 epilogue output
    __bf16* kl = kh + (size_t)MRr * AHc;
    __bf16* vt = (__bf16*)mvs;                      // z=2 epilogue output (transposed V)
    __bf16* qh = vt + (size_t)MRr * AHc;            // z=0 epilogue output

    // d_out scratch: Whi (2.95 MB) + vbf (6.3 MB) — dead after k_gemm5
    __bf16* Whi = (__bf16*)d_out;
    __bf16* vbf = Whi + (size_t)5 * AHc * HIDC;

    k_pre<<<6588, 256, 0, stream>>>(Wq, Wk, Wv, coW, pww, cob, sepb, td, mask,
                                    Kin, dww, Q, V, Whi, biasb, tdsm,
                                    dwbf, qbf, vbf);

    dim3 gg(AHc / 128, MRr / 128, 5);   // 3 x 32 x 5
    k_gemm5<<<gg, 256, 0, stream>>>(qbf, Kin, vbf, dwbf, Whi, biasb, mq, kh, kl, qh, vt);

    k_ckconv<<<MRr / 4, 256, 0, stream>>>(mkc, mq, ckW, ckb, co, out);

    dim3 ga(64, 24);                    // 1536 blocks
    k_attn<<<ga, 512, 0, stream>>>(qh, kh, kl, vt, mask, tdsm, gam, out);
}